// Round 1
// baseline (335.893 us; speedup 1.0000x reference)
//
#include <hip/hip_runtime.h>

typedef unsigned short u16;
typedef __attribute__((ext_vector_type(8))) __bf16 bf16x8;
typedef __attribute__((ext_vector_type(4))) float f32x4;
typedef __attribute__((ext_vector_type(4))) unsigned int u32x4;

#define MFMA16(a, b, c) __builtin_amdgcn_mfma_f32_16x16x32_bf16(a, b, c, 0, 0, 0)

__device__ __forceinline__ u16 f2bf(float f) {
    unsigned u = __float_as_uint(f);
    u = (u + 0x7FFFu + ((u >> 16) & 1u)) >> 16;
    return (u16)u;
}

static constexpr int Bv = 2, Tv = 2048, Cv = 1024, Hv = 16, Dv = 64;
static constexpr int Mv = Bv * Tv; // 4096

// ws element offsets (u16 elements)
static constexpr size_t OFF_XB = 0;                      // x bf16       [4096,1024]
static constexpr size_t OFF_WQ = 4194304;                // Wq bf16      [1024,1024]
static constexpr size_t OFF_WK = OFF_WQ + 1048576;
static constexpr size_t OFF_WV = OFF_WK + 1048576;
static constexpr size_t OFF_WO = OFF_WV + 1048576;
static constexpr size_t OFF_Q  = OFF_WO + 1048576;       // Q bf16 [B,T,H,D]
static constexpr size_t OFF_K  = OFF_Q + 4194304;
static constexpr size_t OFF_V  = OFF_K + 4194304;
static constexpr size_t OFF_A  = OFF_V + 4194304;        // attended bf16 [B,T,H,D]

// ---------------- fp32 -> bf16 convert (x + 4 weights) ----------------
__global__ __launch_bounds__(256) void convert_all(
    const float* __restrict__ x,
    const float* __restrict__ wq, const float* __restrict__ wk,
    const float* __restrict__ wv, const float* __restrict__ wo,
    u16* __restrict__ dst)
{
    int i4 = blockIdx.x * blockDim.x + threadIdx.x;
    if (i4 >= 2097152) return;              // (4M + 4*1M)/4 elems
    int idx = i4 * 4;
    const float* src; int off;
    if (idx < 4194304) { src = x; off = idx; }
    else {
        int rel = idx - 4194304;
        int j = rel >> 20;                  // which weight
        off = rel & 1048575;
        src = (j == 0) ? wq : (j == 1) ? wk : (j == 2) ? wv : wo;
    }
    float4 v = *(const float4*)(src + off);
    ushort4 o;
    o.x = f2bf(v.x); o.y = f2bf(v.y); o.z = f2bf(v.z); o.w = f2bf(v.w);
    *(ushort4*)(dst + idx) = o;
}

// ---------------- bf16 GEMM: out[M,N] = A[M,K] * W[N,K]^T + bias ----------------
// 64x64 tile per block, 4 waves, each wave 16 rows x 64 cols, 16x16x32 MFMA.
template <bool OUT_BF16>
__global__ __launch_bounds__(256) void gemm_bt(
    const u16* __restrict__ A,      // [M,K] bf16
    const u16* __restrict__ Wt,     // [N,K] bf16 (row n = output col n)
    const float* __restrict__ bias, // [N]
    void* __restrict__ outp,
    int M, int N, int K)
{
    __shared__ u16 lA[64][40];  // 32 k-elems per row, pad to 40 (80B rows, 16B aligned)
    __shared__ u16 lB[64][40];
    const int tid  = threadIdx.x;
    const int lane = tid & 63, w = tid >> 6;
    const int quad = lane >> 4, lm = lane & 15;
    const int m0 = blockIdx.y * 64, n0 = blockIdx.x * 64;

    f32x4 zero = {0.f, 0.f, 0.f, 0.f};
    f32x4 acc[4];
    #pragma unroll
    for (int nt = 0; nt < 4; nt++) acc[nt] = zero;

    const int srow = tid >> 2, sseg = tid & 3;   // 64 rows x 4 segs of 8 elems

    for (int k0 = 0; k0 < K; k0 += 32) {
        u32x4 va = *(const u32x4*)(A  + (size_t)(m0 + srow) * K + k0 + sseg * 8);
        u32x4 vb = *(const u32x4*)(Wt + (size_t)(n0 + srow) * K + k0 + sseg * 8);
        *(u32x4*)&lA[srow][sseg * 8] = va;
        *(u32x4*)&lB[srow][sseg * 8] = vb;
        __syncthreads();
        // A-frag: A[m = lm][k = quad*8 + i]
        bf16x8 af = *(const bf16x8*)&lA[w * 16 + lm][quad * 8];
        #pragma unroll
        for (int nt = 0; nt < 4; nt++) {
            // B-frag: B[k = quad*8+i][n = lm] = W[n][k]
            bf16x8 bf = *(const bf16x8*)&lB[nt * 16 + lm][quad * 8];
            acc[nt] = MFMA16(af, bf, acc[nt]);
        }
        __syncthreads();
    }

    // C/D layout: row = quad*4 + r, col = lm (within 16x16 tile)
    #pragma unroll
    for (int nt = 0; nt < 4; nt++) {
        int col = n0 + nt * 16 + lm;
        float bv = bias[col];
        #pragma unroll
        for (int r = 0; r < 4; r++) {
            int row = m0 + w * 16 + quad * 4 + r;
            float v = acc[nt][r] + bv;
            if (OUT_BF16) ((u16*)outp)[(size_t)row * N + col] = f2bf(v);
            else          ((float*)outp)[(size_t)row * N + col] = v;
        }
    }
}

// ---------------- flash attention (bf16 MFMA, online softmax) ----------------
// grid: (T/64, H, B); block 256 = 4 waves; wave w owns q rows [qb+16w, qb+16w+16)
__global__ __launch_bounds__(256) void attn(
    const u16* __restrict__ Qp, const u16* __restrict__ Kp,
    const u16* __restrict__ Vp, u16* __restrict__ Op)
{
    __shared__ u16 lK[64][72];        // K-tile: [key][d], pad 72
    __shared__ u16 lVT[64][72];       // V-tile transposed: [d][key]
    __shared__ u16 lP[4][16][72];     // per-wave P: [qrow][key]

    const int tid  = threadIdx.x;
    const int lane = tid & 63, w = tid >> 6;
    const int quad = lane >> 4, lm = lane & 15;
    const int qt = blockIdx.x, h = blockIdx.y, b = blockIdx.z;
    const int qb = qt * 64;
    const size_t headoff = (size_t)b * Tv * Cv + (size_t)h * Dv;  // (b, t=0, h, d=0)
    const int rs = Cv;  // row stride in elems between consecutive t

    // Q A-frags (held in regs): A[m=lm][k = ks*32 + quad*8 + i]
    bf16x8 qf[2];
    {
        const u16* qptr = Qp + headoff + (size_t)(qb + w * 16 + lm) * rs + quad * 8;
        qf[0] = *(const bf16x8*)(qptr);
        qf[1] = *(const bf16x8*)(qptr + 32);
    }

    f32x4 zero = {0.f, 0.f, 0.f, 0.f};
    f32x4 oacc[4];
    #pragma unroll
    for (int nt = 0; nt < 4; nt++) oacc[nt] = zero;
    float Mr[4], Lr[4];
    #pragma unroll
    for (int r = 0; r < 4; r++) { Mr[r] = -__builtin_inff(); Lr[r] = 0.f; }

    const float SC = 0.18033688011112042f;  // (1/sqrt(64)) * log2(e)
    const int srow = tid >> 2;              // staging: key index 0..63

    for (int kt = 0; kt <= qt; kt++) {
        const int k0 = kt * 64;
        // ---- stage K (row-major) and V (transposed) ----
        {
            const u16* kbase = Kp + headoff + (size_t)(k0 + srow) * rs;
            const u16* vbase = Vp + headoff + (size_t)(k0 + srow) * rs;
            #pragma unroll
            for (int s2 = 0; s2 < 2; s2++) {
                int seg = (tid & 3) + s2 * 4;      // 0..7, 8 d-elems each
                u32x4 kv = *(const u32x4*)(kbase + seg * 8);
                *(u32x4*)&lK[srow][seg * 8] = kv;
                union { u32x4 v; u16 e[8]; } uu;
                uu.v = *(const u32x4*)(vbase + seg * 8);
                #pragma unroll
                for (int j = 0; j < 8; j++) lVT[seg * 8 + j][srow] = uu.e[j];
            }
        }
        __syncthreads();

        // ---- S = Q K^T ----
        f32x4 sacc[4];
        #pragma unroll
        for (int nt = 0; nt < 4; nt++) sacc[nt] = zero;
        #pragma unroll
        for (int ks = 0; ks < 2; ks++) {
            #pragma unroll
            for (int nt = 0; nt < 4; nt++) {
                // B-frag: B[k=d][n=key] = K[key][d]
                bf16x8 bf = *(const bf16x8*)&lK[nt * 16 + lm][ks * 32 + quad * 8];
                sacc[nt] = MFMA16(qf[ks], bf, sacc[nt]);
            }
        }

        // ---- online softmax (log2 domain). S rows = quad*4 + r (matches O rows) ----
        #pragma unroll
        for (int r = 0; r < 4; r++) {
            const int qrow = qb + w * 16 + quad * 4 + r;
            float s[4];
            #pragma unroll
            for (int nt = 0; nt < 4; nt++) {
                int key = k0 + nt * 16 + lm;
                float sv = sacc[nt][r] * SC;
                s[nt] = (key > qrow) ? -__builtin_inff() : sv;
            }
            float m = fmaxf(fmaxf(s[0], s[1]), fmaxf(s[2], s[3]));
            #pragma unroll
            for (int off = 1; off < 16; off <<= 1)
                m = fmaxf(m, __shfl_xor(m, off, 64));
            float Mn = fmaxf(Mr[r], m);
            float alpha = exp2f(Mr[r] - Mn);
            Mr[r] = Mn;
            float p[4], psum = 0.f;
            #pragma unroll
            for (int nt = 0; nt < 4; nt++) { p[nt] = exp2f(s[nt] - Mn); psum += p[nt]; }
            #pragma unroll
            for (int off = 1; off < 16; off <<= 1)
                psum += __shfl_xor(psum, off, 64);
            Lr[r] = Lr[r] * alpha + psum;
            #pragma unroll
            for (int nt = 0; nt < 4; nt++) oacc[nt][r] *= alpha;
            // write P (C-layout) to per-wave LDS region
            #pragma unroll
            for (int nt = 0; nt < 4; nt++)
                lP[w][quad * 4 + r][nt * 16 + lm] = f2bf(p[nt]);
        }

        // ---- O += P V  (P re-read in A-layout; V^T gives contiguous B-frags) ----
        #pragma unroll
        for (int ks = 0; ks < 2; ks++) {
            bf16x8 pf = *(const bf16x8*)&lP[w][lm][ks * 32 + quad * 8];
            #pragma unroll
            for (int nt = 0; nt < 4; nt++) {
                // B-frag: B[k=key][n=d] = V[key][d] = lVT[d][key]
                bf16x8 vf = *(const bf16x8*)&lVT[nt * 16 + lm][ks * 32 + quad * 8];
                oacc[nt] = MFMA16(pf, vf, oacc[nt]);
            }
        }
        __syncthreads();
    }

    // ---- epilogue: O / L, write attended bf16 [B,T,H,D] ----
    #pragma unroll
    for (int nt = 0; nt < 4; nt++) {
        #pragma unroll
        for (int r = 0; r < 4; r++) {
            int row = qb + w * 16 + quad * 4 + r;
            float v = oacc[nt][r] / Lr[r];
            Op[headoff + (size_t)row * rs + nt * 16 + lm] = f2bf(v);
        }
    }
}

// ---------------- launcher ----------------
extern "C" void kernel_launch(void* const* d_in, const int* in_sizes, int n_in,
                              void* d_out, int out_size, void* d_ws, size_t ws_size,
                              hipStream_t stream) {
    const float* x  = (const float*)d_in[0];
    const float* Wq = (const float*)d_in[1];
    const float* bq = (const float*)d_in[2];
    const float* Wk = (const float*)d_in[3];
    const float* bk = (const float*)d_in[4];
    const float* Wv = (const float*)d_in[5];
    const float* bv = (const float*)d_in[6];
    const float* Wo = (const float*)d_in[7];
    const float* bo = (const float*)d_in[8];
    u16* ws = (u16*)d_ws;

    convert_all<<<8192, 256, 0, stream>>>(x, Wq, Wk, Wv, Wo, ws);

    dim3 gg(Cv / 64, Mv / 64);
    gemm_bt<true><<<gg, 256, 0, stream>>>(ws + OFF_XB, ws + OFF_WQ, bq, ws + OFF_Q, Mv, Cv, Cv);
    gemm_bt<true><<<gg, 256, 0, stream>>>(ws + OFF_XB, ws + OFF_WK, bk, ws + OFF_K, Mv, Cv, Cv);
    gemm_bt<true><<<gg, 256, 0, stream>>>(ws + OFF_XB, ws + OFF_WV, bv, ws + OFF_V, Mv, Cv, Cv);

    attn<<<dim3(Tv / 64, Hv, Bv), 256, 0, stream>>>(ws + OFF_Q, ws + OFF_K, ws + OFF_V, ws + OFF_A);

    gemm_bt<false><<<gg, 256, 0, stream>>>(ws + OFF_A, ws + OFF_WO, bo, d_out, Mv, Cv, Cv);
}

// Round 2
// 223.722 us; speedup vs baseline: 1.5014x; 1.5014x over previous
//
#include <hip/hip_runtime.h>

typedef unsigned short u16;
typedef __attribute__((ext_vector_type(8))) __bf16 bf16x8;
typedef __attribute__((ext_vector_type(4))) __bf16 bf16x4;
typedef __attribute__((ext_vector_type(4))) float f32x4;
typedef __attribute__((ext_vector_type(4))) unsigned int u32x4;

#define MFMA16(a, b, c) __builtin_amdgcn_mfma_f32_16x16x32_bf16(a, b, c, 0, 0, 0)

__device__ __forceinline__ u16 f2bf(float f) {
    unsigned u = __float_as_uint(f);
    u = (u + 0x7FFFu + ((u >> 16) & 1u)) >> 16;
    return (u16)u;
}

// async global->LDS, 16B per lane; LDS dest = wave-uniform base + lane*16
__device__ __forceinline__ void gl_lds16(const u16* g, u16* l) {
    __builtin_amdgcn_global_load_lds(
        (const __attribute__((address_space(1))) unsigned int*)g,
        (__attribute__((address_space(3))) unsigned int*)l, 16, 0, 0);
}

static constexpr int Bv = 2, Tv = 2048, Cv = 1024, Hv = 16, Dv = 64;
static constexpr int Mv = Bv * Tv; // 4096

// ws element offsets (u16 elements)
static constexpr size_t OFF_XB = 0;                      // x bf16       [4096,1024]
static constexpr size_t OFF_WQ = 4194304;                // Wq bf16      [1024,1024]
static constexpr size_t OFF_WK = OFF_WQ + 1048576;
static constexpr size_t OFF_WV = OFF_WK + 1048576;
static constexpr size_t OFF_WO = OFF_WV + 1048576;
static constexpr size_t OFF_Q  = OFF_WO + 1048576;       // Q bf16 [M, C] (col = h*64+d)
static constexpr size_t OFF_K  = OFF_Q + 4194304;
static constexpr size_t OFF_V  = OFF_K + 4194304;
static constexpr size_t OFF_A  = OFF_V + 4194304;        // attended bf16 [M, C]

// ---------------- fp32 -> bf16 convert (x + 4 weights) ----------------
__global__ __launch_bounds__(256) void convert_all(
    const float* __restrict__ x,
    const float* __restrict__ wq, const float* __restrict__ wk,
    const float* __restrict__ wv, const float* __restrict__ wo,
    u16* __restrict__ dst)
{
    int i4 = blockIdx.x * blockDim.x + threadIdx.x;
    if (i4 >= 2097152) return;
    int idx = i4 * 4;
    const float* src; int off;
    if (idx < 4194304) { src = x; off = idx; }
    else {
        int rel = idx - 4194304;
        int j = rel >> 20;
        off = rel & 1048575;
        src = (j == 0) ? wq : (j == 1) ? wk : (j == 2) ? wv : wo;
    }
    float4 v = *(const float4*)(src + off);
    ushort4 o;
    o.x = f2bf(v.x); o.y = f2bf(v.y); o.z = f2bf(v.z); o.w = f2bf(v.w);
    *(ushort4*)(dst + idx) = o;
}

// ---------------- 128x128-tile bf16 GEMM body (m97 structure) ----------------
// out[M,N] = A[M,K] * W[N,K]^T + bias. 256 thr = 4 waves in 2x2, each wave 64x64.
template <bool OUT_BF16>
__device__ __forceinline__ void gemm128_body(
    const u16* __restrict__ A, const u16* __restrict__ Wt,
    const float* __restrict__ bias, void* __restrict__ outp,
    int m0, int n0, int N, int K)
{
    __shared__ u16 lA[128 * 32];
    __shared__ u16 lB[128 * 32];
    const int tid  = threadIdx.x;
    const int lane = tid & 63, w = tid >> 6;
    const int quad = lane >> 4, lm = lane & 15;
    const int wm = (w & 1) * 64, wn = (w >> 1) * 64;

    f32x4 zero = {0.f, 0.f, 0.f, 0.f};
    f32x4 acc[4][4];
    #pragma unroll
    for (int mt = 0; mt < 4; mt++)
        #pragma unroll
        for (int nt = 0; nt < 4; nt++) acc[mt][nt] = zero;

    // staging: each wave stages rows [w*16, w*16+16) and [64+w*16, ...) of A and B
    const int srow = lane >> 2, sseg = lane & 3;   // 16 rows x 4 segs(16B) = 1KB/instr
    const u16* ga0 = A  + (size_t)(m0 + w * 16 + srow) * K + sseg * 8;
    const u16* ga1 = ga0 + (size_t)64 * K;
    const u16* gb0 = Wt + (size_t)(n0 + w * 16 + srow) * K + sseg * 8;
    const u16* gb1 = gb0 + (size_t)64 * K;
    u16* la0 = &lA[(w * 16) * 32];      u16* la1 = &lA[(64 + w * 16) * 32];
    u16* lb0 = &lB[(w * 16) * 32];      u16* lb1 = &lB[(64 + w * 16) * 32];

    for (int k0 = 0; k0 < K; k0 += 32) {
        gl_lds16(ga0 + k0, la0);
        gl_lds16(ga1 + k0, la1);
        gl_lds16(gb0 + k0, lb0);
        gl_lds16(gb1 + k0, lb1);
        __syncthreads();   // drains vmcnt: LDS tiles ready
        bf16x8 af[4], bf[4];
        #pragma unroll
        for (int mt = 0; mt < 4; mt++)
            af[mt] = *(const bf16x8*)&lA[(wm + mt * 16 + lm) * 32 + quad * 8];
        #pragma unroll
        for (int nt = 0; nt < 4; nt++)
            bf[nt] = *(const bf16x8*)&lB[(wn + nt * 16 + lm) * 32 + quad * 8];
        #pragma unroll
        for (int mt = 0; mt < 4; mt++)
            #pragma unroll
            for (int nt = 0; nt < 4; nt++)
                acc[mt][nt] = MFMA16(af[mt], bf[nt], acc[mt][nt]);
        __syncthreads();   // reads done before next-iter staging overwrites
    }

    #pragma unroll
    for (int nt = 0; nt < 4; nt++) {
        int col = n0 + wn + nt * 16 + lm;
        float bv = bias[col];
        #pragma unroll
        for (int mt = 0; mt < 4; mt++) {
            #pragma unroll
            for (int r = 0; r < 4; r++) {
                int row = m0 + wm + mt * 16 + quad * 4 + r;
                float v = acc[mt][nt][r] + bv;
                if (OUT_BF16) ((u16*)outp)[(size_t)row * N + col] = f2bf(v);
                else          ((float*)outp)[(size_t)row * N + col] = v;
            }
        }
    }
}

// fused QKV: grid (24, 32); block x in [0,8) -> Q, [8,16) -> K, [16,24) -> V
__global__ __launch_bounds__(256) void gemm_qkv(
    const u16* __restrict__ A,
    const u16* __restrict__ Wq, const u16* __restrict__ Wk, const u16* __restrict__ Wv,
    const float* __restrict__ bq, const float* __restrict__ bk, const float* __restrict__ bv,
    u16* __restrict__ Q, u16* __restrict__ K, u16* __restrict__ V)
{
    int nb = blockIdx.x;
    int which = nb >> 3;
    int n0 = (nb & 7) * 128;
    const u16* Wt = (which == 0) ? Wq : (which == 1) ? Wk : Wv;
    const float* bias = (which == 0) ? bq : (which == 1) ? bk : bv;
    u16* out = (which == 0) ? Q : (which == 1) ? K : V;
    gemm128_body<true>(A, Wt, bias, out, blockIdx.y * 128, n0, Cv, Cv);
}

__global__ __launch_bounds__(256) void gemm_o(
    const u16* __restrict__ A, const u16* __restrict__ Wt,
    const float* __restrict__ bias, float* __restrict__ outp)
{
    gemm128_body<false>(A, Wt, bias, outp, blockIdx.y * 128, blockIdx.x * 128, Cv, Cv);
}

// ---------------- flash attention: fixed-exponent softmax, no cross-lane in loop ----------------
// grid: (32, H, B) with qt reversed; block 256 = 4 waves; wave w owns 16 q-rows.
__global__ __launch_bounds__(256) void attn(
    const u16* __restrict__ Qp, const u16* __restrict__ Kp,
    const u16* __restrict__ Vp, u16* __restrict__ Op)
{
    __shared__ u16 lK[64 * 64];       // K-tile [key][d], columns XOR-swizzled by (key&7)
    __shared__ u16 lVT[64][72];       // V-tile transposed [d][key], pad 72
    __shared__ u16 lP[4][16][68];     // per-wave P [qrow][key], pad 68 (2-way-free writes)

    const int tid  = threadIdx.x;
    const int lane = tid & 63, w = tid >> 6;
    const int quad = lane >> 4, lm = lane & 15;
    const int qt = 31 - blockIdx.x;   // reversed: long blocks first
    const int h = blockIdx.y, b = blockIdx.z;
    const int qb = qt * 64;
    const size_t headoff = (size_t)b * Tv * Cv + (size_t)h * Dv;
    const int rs = Cv;

    // Q A-frags in regs: A[m=lm][k = ks*32 + quad*8 + i]
    bf16x8 qf[2];
    {
        const u16* qptr = Qp + headoff + (size_t)(qb + w * 16 + lm) * rs + quad * 8;
        qf[0] = *(const bf16x8*)(qptr);
        qf[1] = *(const bf16x8*)(qptr + 32);
    }

    f32x4 zero = {0.f, 0.f, 0.f, 0.f};
    f32x4 oacc[4];
    #pragma unroll
    for (int nt = 0; nt < 4; nt++) oacc[nt] = zero;
    float Lp[4] = {0.f, 0.f, 0.f, 0.f};

    const float SC = 0.18033688011112042f;  // (1/sqrt(64)) * log2(e)

    const int rowi = lane >> 3, seg = lane & 7;   // K staging ids
    const int vd = tid & 63, vkb = tid >> 6;      // V gather ids: d, key-block(16)

    for (int kt = 0; kt <= qt; kt++) {
        const int k0 = kt * 64;
        // ---- stage K via swizzled global_load_lds (2 instrs/wave, 8 rows each) ----
        #pragma unroll
        for (int half = 0; half < 2; half++) {
            int rbase = w * 16 + half * 8;
            int row = rbase + rowi;
            int gseg = seg ^ (row & 7);
            gl_lds16(Kp + headoff + (size_t)(k0 + row) * rs + gseg * 8, &lK[rbase * 64]);
        }
        // ---- stage V^T: coalesced strided gather + contiguous b128 writes ----
        {
            const u16* vb = Vp + headoff + (size_t)(k0 + vkb * 16) * rs + vd;
            union { u16 e[16]; u32x4 v[2]; } tmp;
            #pragma unroll
            for (int j = 0; j < 16; j++) tmp.e[j] = vb[(size_t)j * rs];
            *(u32x4*)&lVT[vd][vkb * 16]     = tmp.v[0];
            *(u32x4*)&lVT[vd][vkb * 16 + 8] = tmp.v[1];
        }
        __syncthreads();

        // ---- S = Q K^T ----
        f32x4 sacc[4];
        #pragma unroll
        for (int nt = 0; nt < 4; nt++) sacc[nt] = zero;
        #pragma unroll
        for (int ks = 0; ks < 2; ks++) {
            #pragma unroll
            for (int nt = 0; nt < 4; nt++) {
                bf16x8 kf = *(const bf16x8*)
                    &lK[(nt * 16 + lm) * 64 + (((ks * 4 + quad) ^ (lm & 7)) * 8)];
                sacc[nt] = MFMA16(qf[ks], kf, sacc[nt]);
            }
        }

        // ---- fixed-exponent softmax: p = exp2(s*SC - 16); scale cancels in O/L ----
        const bool diag = (kt == qt);
        #pragma unroll
        for (int r = 0; r < 4; r++) {
            const int qrow = qb + w * 16 + quad * 4 + r;
            #pragma unroll
            for (int nt = 0; nt < 4; nt++) {
                float e = __builtin_amdgcn_exp2f(fmaf(sacc[nt][r], SC, -16.f));
                if (diag && (k0 + nt * 16 + lm > qrow)) e = 0.f;
                Lp[r] += e;
                lP[w][quad * 4 + r][nt * 16 + lm] = (u16)(__float_as_uint(e) >> 16);
            }
        }

        // ---- O += P V ----
        #pragma unroll
        for (int ks = 0; ks < 2; ks++) {
            union { bf16x8 v8; bf16x4 v4[2]; } pu;
            pu.v4[0] = *(const bf16x4*)&lP[w][lm][ks * 32 + quad * 8];
            pu.v4[1] = *(const bf16x4*)&lP[w][lm][ks * 32 + quad * 8 + 4];
            #pragma unroll
            for (int nt = 0; nt < 4; nt++) {
                bf16x8 vf = *(const bf16x8*)&lVT[nt * 16 + lm][ks * 32 + quad * 8];
                oacc[nt] = MFMA16(pu.v8, vf, oacc[nt]);
            }
        }
        __syncthreads();
    }

    // ---- epilogue: single deferred L reduction, then O/L ----
    float inv[4];
    #pragma unroll
    for (int r = 0; r < 4; r++) {
        float L = Lp[r];
        #pragma unroll
        for (int off = 1; off < 16; off <<= 1)
            L += __shfl_xor(L, off, 64);
        inv[r] = 1.0f / L;
    }
    #pragma unroll
    for (int nt = 0; nt < 4; nt++) {
        #pragma unroll
        for (int r = 0; r < 4; r++) {
            int row = qb + w * 16 + quad * 4 + r;
            Op[headoff + (size_t)row * rs + nt * 16 + lm] = f2bf(oacc[nt][r] * inv[r]);
        }
    }
}

// ---------------- launcher ----------------
extern "C" void kernel_launch(void* const* d_in, const int* in_sizes, int n_in,
                              void* d_out, int out_size, void* d_ws, size_t ws_size,
                              hipStream_t stream) {
    const float* x  = (const float*)d_in[0];
    const float* Wq = (const float*)d_in[1];
    const float* bq = (const float*)d_in[2];
    const float* Wk = (const float*)d_in[3];
    const float* bk = (const float*)d_in[4];
    const float* Wv = (const float*)d_in[5];
    const float* bv = (const float*)d_in[6];
    const float* Wo = (const float*)d_in[7];
    const float* bo = (const float*)d_in[8];
    u16* ws = (u16*)d_ws;

    convert_all<<<8192, 256, 0, stream>>>(x, Wq, Wk, Wv, Wo, ws);

    gemm_qkv<<<dim3(24, 32), 256, 0, stream>>>(
        ws + OFF_XB, ws + OFF_WQ, ws + OFF_WK, ws + OFF_WV,
        bq, bk, bv, ws + OFF_Q, ws + OFF_K, ws + OFF_V);

    attn<<<dim3(32, Hv, Bv), 256, 0, stream>>>(ws + OFF_Q, ws + OFF_K, ws + OFF_V, ws + OFF_A);

    gemm_o<<<dim3(8, 32), 256, 0, stream>>>(ws + OFF_A, ws + OFF_WO, bo, (float*)d_out);
}